// Round 6
// baseline (692.886 us; speedup 1.0000x reference)
//
#include <hip/hip_runtime.h>
#include <math.h>

#define NBATCH 4
#define NP 4096
#define BN (NBATCH*NP)
#define KCAP 256

typedef unsigned short u16; typedef unsigned int u32; typedef unsigned long long u64;
typedef __attribute__((ext_vector_type(4))) float f4;
typedef __attribute__((ext_vector_type(8))) __bf16 b8;

__device__ __forceinline__ void load16(const float* __restrict__ p, float* d){
  const f4* q = (const f4*)p;
  f4 a0=q[0], a1=q[1], a2=q[2], a3=q[3];
#pragma unroll
  for (int e=0;e<4;++e){ d[e]=a0[e]; d[4+e]=a1[e]; d[8+e]=a2[e]; d[12+e]=a3[e]; }
}

// 16 KB [256 c][32 k] staging tile swizzle (k_mlp / k_attn / k_out)
__device__ __forceinline__ int waddr(int c, int u){
  return ((c*64) ^ ((c&16)<<2)) + (((u ^ (c>>5)) & 3)<<4);
}
__device__ __forceinline__ void stageW(const __bf16* __restrict__ wsrc, int kb, __bf16* lds, int tid){
#pragma unroll
  for (int p=0;p<4;++p){
    int flat = p*256 + tid;
    int c = flat>>2, u = flat&3;
    b8 v = *(const b8*)(wsrc + (size_t)c*256 + kb*32 + u*8);
    *(b8*)((char*)lds + waddr(c,u)) = v;
  }
}
__device__ __forceinline__ b8 readB(const __bf16* lds, int c, int lq){
  return *(const b8*)((const char*)lds + waddr(c,lq));
}

// ---------------------------------------------------------------- y<9: transpose 9 f32 mats -> bf16 [out][in]
// y==9: pos -> pos4 ; y==10: x f32 -> bf16
__global__ __launch_bounds__(256) void k_wt9(
    const float* a0,const float* a1,const float* a2,const float* a3,const float* a4,
    const float* a5,const float* a6,const float* a7,const float* a8, __bf16* wt,
    const float* __restrict__ pos, float* __restrict__ pos4,
    const float* __restrict__ x, __bf16* __restrict__ xb)
{
  __shared__ float T[32][33];
  int m = blockIdx.y;
  if (m == 9){
    int n = blockIdx.x*256 + threadIdx.x;
    f4 v = {pos[n*3+0], pos[n*3+1], pos[n*3+2], 0.0f};
    ((f4*)pos4)[n] = v;
    return;
  }
  if (m == 10){
    int base = (blockIdx.x*256 + threadIdx.x);
    for (int it=0; it<32; ++it){
      int i = (base + it*16384)*8;
      f4 a = ((const f4*)(x+i))[0];
      f4 b = ((const f4*)(x+i))[1];
      b8 o;
#pragma unroll
      for (int e=0;e<4;++e){ o[e]=(__bf16)a[e]; o[4+e]=(__bf16)b[e]; }
      *(b8*)(xb+i) = o;
    }
    return;
  }
  const float* s;
  switch(m){ case 0:s=a0;break; case 1:s=a1;break; case 2:s=a2;break; case 3:s=a3;break;
             case 4:s=a4;break; case 5:s=a5;break; case 6:s=a6;break; case 7:s=a7;break; default:s=a8;break; }
  int tile = blockIdx.x;
  int ti = (tile>>3)*32, to = (tile&7)*32;
  int tx = threadIdx.x & 31, ty = threadIdx.x >> 5;
#pragma unroll
  for (int rr=0;rr<4;++rr){
    int i = ti + ty + rr*8;
    T[tx][ty+rr*8] = s[(size_t)i*256 + to + tx];
  }
  __syncthreads();
#pragma unroll
  for (int rr=0;rr<4;++rr){
    int o = to + ty + rr*8;
    wt[(size_t)m*65536 + (size_t)o*256 + ti + tx] = (__bf16)T[ty+rr*8][tx];
  }
}

// ---------------------------------------------------------------- exact KNN (top-16 by (d2,idx)) — R3 1-row version
__global__ __launch_bounds__(256,2) void k_knn(const float* __restrict__ pos, int* __restrict__ knnout){
#pragma clang fp contract(off)
  __shared__ f4  lp[NP];          // x,y,z,sq  (64 KB)
  __shared__ u64 buf[4][KCAP];
  int tid = threadIdx.x, lane = tid & 63, w = tid >> 6;
  int b = blockIdx.y;
  int rowbase = blockIdx.x * 32;

  for (int i = tid; i < NP; i += 256){
    float x = pos[(size_t)(b*NP+i)*3+0];
    float y = pos[(size_t)(b*NP+i)*3+1];
    float z = pos[(size_t)(b*NP+i)*3+2];
    f4 v = {x, y, z, (x*x + y*y) + z*z};
    lp[i] = v;
  }
  __syncthreads();

  for (int it = 0; it < 8; ++it){
    int n = rowbase + w*8 + it;
    f4 pn = lp[n];
    float xn=pn[0], yn=pn[1], zn=pn[2], sqn=pn[3];

    float d2s[64];
    float mn = 3.4e38f;
#pragma unroll
    for (int t = 0; t < 64; ++t){
      int j = t*64 + lane;
      f4 pm = lp[j];
      float dot = (xn*pm[0] + yn*pm[1]) + zn*pm[2];
      float d2 = (sqn + pm[3]) - 2.0f*dot;
      d2 = fmaxf(d2, 0.0f);
      d2s[t] = d2;
      mn = fminf(mn, d2);
    }
    float v = mn;
#pragma unroll
    for (int k = 2; k <= 64; k <<= 1){
#pragma unroll
      for (int j = k>>1; j >= 1; j >>= 1){
        float o = __shfl_xor(v, j, 64);
        float lo = fminf(v,o), hi = fmaxf(v,o);
        v = (((lane & k) == 0) == ((lane & j) == 0)) ? lo : hi;
      }
    }
    float T1 = __shfl(v, 15, 64);   // >=16 candidates have d2 <= T1

    int cnt = 0;
    u64* mybuf = buf[w];
#pragma unroll
    for (int t = 0; t < 64; ++t){
      bool pass = (d2s[t] <= T1);
      u64 mk = __ballot(pass);
      if (pass){
        int p = cnt + __popcll(mk & ((1ull<<lane)-1ull));
        if (p < KCAP) mybuf[p] = (((u64)__float_as_uint(d2s[t]))<<32) | (u32)(t*64+lane);
      }
      cnt += __popcll(mk);
    }
    int* orow = knnout + (size_t)(b*NP + n)*16;
    if (cnt <= KCAP){
      for (int base = 0; base < cnt; base += 64){
        int e = base + lane;
        u64 mykey = (e < cnt) ? mybuf[e] : ~0ull;
        int rank = 0;
        for (int m2 = 0; m2 < cnt; ++m2) rank += (mybuf[m2] < mykey) ? 1 : 0;
        if (e < cnt && rank < 16) orow[rank] = b*NP + (int)(u32)(mykey & 0xffffffffull);
      }
    } else {
      float dd[16]; int ii[16];
#pragma unroll
      for (int i2=0;i2<16;++i2){ dd[i2]=3.4e38f; ii[i2]=0x7fffffff; }
#pragma unroll
      for (int t=0;t<64;++t){
        float d2 = d2s[t]; int j = t*64+lane;
        if (d2 < dd[15]){
#pragma unroll
          for (int i2=15;i2>0;--i2){
            bool up  = d2 < dd[i2-1];
            bool in2 = d2 < dd[i2];
            float nv = up ? dd[i2-1] : (in2 ? d2 : dd[i2]);
            int   ni = up ? ii[i2-1] : (in2 ? j  : ii[i2]);
            dd[i2]=nv; ii[i2]=ni;
          }
          if (d2 < dd[0]){ dd[0]=d2; ii[0]=j; }
        }
      }
      for (int r=0;r<16;++r){
        u64 key = (((u64)__float_as_uint(dd[0]))<<32) | (u32)ii[0];
        u64 m3 = key;
#pragma unroll
        for (int s=1;s<64;s<<=1){ u64 o3 = __shfl_xor(m3, s, 64); m3 = (o3<m3)?o3:m3; }
        if (key == m3){
#pragma unroll
          for (int i2=0;i2<15;++i2){ dd[i2]=dd[i2+1]; ii[i2]=ii[i2+1]; }
          dd[15]=3.4e38f; ii[15]=0x7fffffff;
        }
        if (lane == r) orow[r] = b*NP + (int)(u32)(m3 & 0xffffffffull);
      }
    }
  }
}

// ---------------------------------------------------------------- fused 2-layer MLP (q/k/v), M=128, LDS-staged B
__global__ __launch_bounds__(256,2) void k_mlp(
  const __bf16* __restrict__ xb, const __bf16* __restrict__ wt,
  const float* qb1,const float* qb2,const float* kb1,const float* kb2,
  const float* vb1,const float* vb2,
  float* __restrict__ qout, __bf16* __restrict__ kfout, __bf16* __restrict__ vfout)
{
  int which = blockIdx.y;
  const __bf16* w1t = wt + (size_t)which*2*65536;
  const __bf16* w2t = w1t + 65536;
  const float* b1 = (which==0)?qb1:((which==1)?kb1:vb1);
  const float* b2 = (which==0)?qb2:((which==1)?kb2:vb2);
  __shared__ __align__(16) __bf16 wstage[8192];
  __shared__ __align__(16) __bf16 hbuf[128*256];
  int tid=threadIdx.x, lane=tid&63, w=tid>>6, lr=lane&15, lq=lane>>4;
  int row0 = blockIdx.x*128;

  float b1f[16], b2f[16];
  load16(b1+16*lr, b1f); load16(b2+16*lr, b2f);

  f4 acc[2][16];
#pragma unroll
  for (int tt=0;tt<2;++tt)
#pragma unroll
    for (int t=0;t<16;++t) acc[tt][t]=(f4){0.f,0.f,0.f,0.f};

  for (int kb=0;kb<8;++kb){
    stageW(w1t, kb, wstage, tid);
    __syncthreads();
    b8 af[2];
#pragma unroll
    for (int tt=0;tt<2;++tt)
      af[tt] = *(const b8*)(xb + (size_t)(row0 + (w+tt*4)*16 + lr)*256 + kb*32 + lq*8);
#pragma unroll
    for (int t=0;t<16;++t){
      b8 bb = readB(wstage, 16*lr+t, lq);
      acc[0][t] = __builtin_amdgcn_mfma_f32_16x16x32_bf16(af[0], bb, acc[0][t], 0,0,0);
      acc[1][t] = __builtin_amdgcn_mfma_f32_16x16x32_bf16(af[1], bb, acc[1][t], 0,0,0);
    }
    __syncthreads();
  }
#pragma unroll
  for (int tt=0;tt<2;++tt){
#pragma unroll
    for (int r=0;r<4;++r){
      int row = (w+tt*4)*16 + 4*lq + r;
      b8 p0,p1;
#pragma unroll
      for (int t=0;t<8;++t){
        p0[t]=(__bf16)fmaxf(acc[tt][t][r]  +b1f[t],  0.f);
        p1[t]=(__bf16)fmaxf(acc[tt][8+t][r]+b1f[8+t],0.f);
      }
      char* hb = (char*)hbuf + row*512;
      *(b8*)(hb + ((((2*lr)  ^(row&7))&31)<<4)) = p0;
      *(b8*)(hb + ((((2*lr+1)^(row&7))&31)<<4)) = p1;
    }
  }
#pragma unroll
  for (int tt=0;tt<2;++tt)
#pragma unroll
    for (int t=0;t<16;++t) acc[tt][t]=(f4){0.f,0.f,0.f,0.f};
  for (int kb=0;kb<8;++kb){
    stageW(w2t, kb, wstage, tid);
    __syncthreads();
    b8 af[2];
#pragma unroll
    for (int tt=0;tt<2;++tt){
      int row = (w+tt*4)*16 + lr;
      af[tt] = *(const b8*)((char*)hbuf + row*512 + ((((kb*4+lq)^(row&7))&31)<<4));
    }
#pragma unroll
    for (int t=0;t<16;++t){
      b8 bb = readB(wstage, 16*lr+t, lq);
      acc[0][t] = __builtin_amdgcn_mfma_f32_16x16x32_bf16(af[0], bb, acc[0][t], 0,0,0);
      acc[1][t] = __builtin_amdgcn_mfma_f32_16x16x32_bf16(af[1], bb, acc[1][t], 0,0,0);
    }
    __syncthreads();
  }
  if (which == 0){
#pragma unroll
    for (int tt=0;tt<2;++tt){
#pragma unroll
      for (int r=0;r<4;++r){
        float* qp = qout + (size_t)(row0 + (w+tt*4)*16 + 4*lq + r)*256 + 16*lr;
#pragma unroll
        for (int u2=0;u2<4;++u2){
          f4 vv;
#pragma unroll
          for (int e2=0;e2<4;++e2)
            vv[e2] = (tt ? acc[1][4*u2+e2][r] : acc[0][4*u2+e2][r]) + b2f[4*u2+e2];
          ((f4*)qp)[u2] = vv;
        }
      }
    }
  } else {
    __bf16* outp = (which==1) ? kfout : vfout;
#pragma unroll
    for (int tt=0;tt<2;++tt){
#pragma unroll
      for (int r=0;r<4;++r){
        b8 p0,p1;
#pragma unroll
        for (int t=0;t<8;++t){
          float a0v = tt ? acc[1][t][r]   : acc[0][t][r];
          float a1v = tt ? acc[1][8+t][r] : acc[0][8+t][r];
          p0[t]=(__bf16)(a0v+b2f[t]);
          p1[t]=(__bf16)(a1v+b2f[8+t]);
        }
        __bf16* op = outp + (size_t)(row0 + (w+tt*4)*16 + 4*lq + r)*256 + 16*lr;
        *(b8*)op = p0; *((b8*)op+1) = p1;
      }
    }
  }
}

// ---------------------------------------------------------------- fused pe-MLP + gather + attention, 8 pts/block (R3)
__global__ __launch_bounds__(256,2) void k_attn(
  const float* __restrict__ normal, const float* __restrict__ pos4,
  const int* __restrict__ knn, const float* __restrict__ qbuf,
  const __bf16* __restrict__ kf, const __bf16* __restrict__ vf,
  const __bf16* __restrict__ wt,
  const float* __restrict__ pw1, const float* __restrict__ pb1, const float* __restrict__ pb2,
  __bf16* __restrict__ o1)
{
  __shared__ __align__(16) __bf16 wstage[8192];
  const __bf16* pw2t = wt + (size_t)6*65536;
  int tid=threadIdx.x, lane=tid&63, w=tid>>6, lr=lane&15, lq=lane>>4;
  int pt0 = blockIdx.x*8 + w;
  int idx[2]; float rv[2], tv[2];
#pragma unroll
  for (int pp=0;pp<2;++pp){
    int p = pt0 + pp*4;
    int j = knn[(size_t)p*16 + lr];
    idx[pp] = j;
    f4 pn = ((const f4*)pos4)[p];
    f4 pj = ((const f4*)pos4)[j];
    float rx=pn[0]-pj[0], ry=pn[1]-pj[1], rz=pn[2]-pj[2];
    float nx=normal[(size_t)p*3], ny=normal[(size_t)p*3+1], nz=normal[(size_t)p*3+2];
    float nn = fmaxf(sqrtf(nx*nx+ny*ny+nz*nz), 1e-12f);
    nx/=nn; ny/=nn; nz/=nn;
    float sqr = rx*rx+ry*ry+rz*rz;
    float r = (sqr>0.f)?sqrtf(sqr):0.f;
    float dt = rx*nx+ry*ny+rz*nz;
    float ratio = fminf(fmaxf(dt/(r+1e-8f),-1.f),1.f);
    rv[pp]=r; tv[pp]=acosf(ratio);
  }

  f4 acc[2][16];
#pragma unroll
  for (int pp=0;pp<2;++pp)
#pragma unroll
    for (int t=0;t<16;++t) acc[pp][t]=(f4){0.f,0.f,0.f,0.f};

  for (int kb=0;kb<8;++kb){
    stageW(pw2t, kb, wstage, tid);
    __syncthreads();
    int kk = kb*32 + lq*8;
    f4 w0a = *(const f4*)(pw1 + kk);
    f4 w0b = *(const f4*)(pw1 + kk + 4);
    f4 w1a = *(const f4*)(pw1 + 256 + kk);
    f4 w1b = *(const f4*)(pw1 + 256 + kk + 4);
    f4 bba = *(const f4*)(pb1 + kk);
    f4 bbb = *(const f4*)(pb1 + kk + 4);
    b8 af[2];
#pragma unroll
    for (int pp=0;pp<2;++pp){
      float r=rv[pp], th=tv[pp];
#pragma unroll
      for (int j2=0;j2<4;++j2){
        af[pp][j2]   = (__bf16)fmaxf(r*w0a[j2] + th*w1a[j2] + bba[j2], 0.f);
        af[pp][4+j2] = (__bf16)fmaxf(r*w0b[j2] + th*w1b[j2] + bbb[j2], 0.f);
      }
    }
#pragma unroll
    for (int t=0;t<16;++t){
      b8 bb = readB(wstage, 16*lr+t, lq);
      acc[0][t] = __builtin_amdgcn_mfma_f32_16x16x32_bf16(af[0], bb, acc[0][t], 0,0,0);
      acc[1][t] = __builtin_amdgcn_mfma_f32_16x16x32_bf16(af[1], bb, acc[1][t], 0,0,0);
    }
    __syncthreads();
  }

  float pb2f[16];
  load16(pb2 + 16*lr, pb2f);
#pragma unroll
  for (int pp=0;pp<2;++pp){
    int ptv = pt0 + pp*4;
    float qv[16];
    load16(qbuf + (size_t)ptv*256 + 16*lr, qv);
    int idxv = idx[pp];
    float sc[4];
#pragma unroll
    for (int r=0;r<4;++r){
      int j = __shfl(idxv, 4*lq + r, 64);
      const b8* kr = (const b8*)(kf + (size_t)j*256 + 16*lr);
      b8 k0 = kr[0], k1 = kr[1];
      float s = 0.f;
#pragma unroll
      for (int t=0;t<8;++t){
        float a0v = pp ? acc[1][t][r]   : acc[0][t][r];
        float a1v = pp ? acc[1][8+t][r] : acc[0][8+t][r];
        s += ((float)k0[t] + a0v + pb2f[t]  ) * qv[t];
        s += ((float)k1[t] + a1v + pb2f[8+t]) * qv[8+t];
      }
      sc[r]=s;
    }
#pragma unroll
    for (int st=1; st<16; st<<=1){
#pragma unroll
      for (int r=0;r<4;++r) sc[r] += __shfl_xor(sc[r], st, 64);
    }
#pragma unroll
    for (int r=0;r<4;++r) sc[r] *= 0.0625f;
    float mx = fmaxf(fmaxf(sc[0],sc[1]), fmaxf(sc[2],sc[3]));
    mx = fmaxf(mx, __shfl_xor(mx,16,64));
    mx = fmaxf(mx, __shfl_xor(mx,32,64));
    float e[4]; float ssum=0.f;
#pragma unroll
    for (int r=0;r<4;++r){ e[r]=expf(sc[r]-mx); ssum+=e[r]; }
    ssum += __shfl_xor(ssum,16,64);
    ssum += __shfl_xor(ssum,32,64);
    float inv = 1.f/ssum;
    float o[16];
#pragma unroll
    for (int t=0;t<16;++t) o[t]=0.f;
#pragma unroll
    for (int r=0;r<4;++r){
      int j = __shfl(idxv, 4*lq + r, 64);
      const b8* vr = (const b8*)(vf + (size_t)j*256 + 16*lr);
      b8 v0 = vr[0], v1 = vr[1];
      float aw = e[r]*inv;
#pragma unroll
      for (int t=0;t<8;++t){
        float a0v = pp ? acc[1][t][r]   : acc[0][t][r];
        float a1v = pp ? acc[1][8+t][r] : acc[0][8+t][r];
        o[t]   += aw*((float)v0[t] + a0v + pb2f[t]);
        o[8+t] += aw*((float)v1[t] + a1v + pb2f[8+t]);
      }
    }
#pragma unroll
    for (int t=0;t<16;++t){
      o[t] += __shfl_xor(o[t],16,64);
      o[t] += __shfl_xor(o[t],32,64);
    }
    if (lq==0){
      b8 p0,p1;
#pragma unroll
      for (int t=0;t<8;++t){ p0[t]=(__bf16)o[t]; p1[t]=(__bf16)o[8+t]; }
      __bf16* op = o1 + (size_t)ptv*256 + 16*lr;
      *(b8*)op = p0; *((b8*)op+1) = p1;
    }
  }
}

// ---------------------------------------------------------------- fc_out + residual + LayerNorm, M=64, f32 out
__global__ __launch_bounds__(256,2) void k_out(
  const __bf16* __restrict__ o1, const __bf16* __restrict__ wt,
  const float* __restrict__ ob1, const float* __restrict__ ob2,
  const float* __restrict__ qbuf,
  const float* __restrict__ lng, const float* __restrict__ lnb,
  float* __restrict__ dout)
{
  const __bf16* w1t = wt + (size_t)7*65536;
  const __bf16* w2t = wt + (size_t)8*65536;
  __shared__ __align__(16) __bf16 wstage[8192];
  __shared__ __align__(16) __bf16 hbuf[64*256];
  int tid=threadIdx.x, lane=tid&63, w=tid>>6, lr=lane&15, lq=lane>>4;
  int row0 = blockIdx.x*64;

  float b1f[16], b2f[16], gf[16], bf2[16];
  load16(ob1+16*lr, b1f); load16(ob2+16*lr, b2f);
  load16(lng+16*lr, gf);  load16(lnb+16*lr, bf2);

  f4 acc[16];
#pragma unroll
  for (int t=0;t<16;++t) acc[t]=(f4){0.f,0.f,0.f,0.f};
  for (int kb=0;kb<8;++kb){
    stageW(w1t, kb, wstage, tid);
    __syncthreads();
    b8 af = *(const b8*)(o1 + (size_t)(row0 + w*16 + lr)*256 + kb*32 + lq*8);
#pragma unroll
    for (int t=0;t<16;++t){
      b8 bb = readB(wstage, 16*lr+t, lq);
      acc[t] = __builtin_amdgcn_mfma_f32_16x16x32_bf16(af, bb, acc[t], 0,0,0);
    }
    __syncthreads();
  }
#pragma unroll
  for (int r=0;r<4;++r){
    int row = w*16 + 4*lq + r;
    b8 p0,p1;
#pragma unroll
    for (int t=0;t<8;++t){
      p0[t]=(__bf16)fmaxf(acc[t][r]  +b1f[t],  0.f);
      p1[t]=(__bf16)fmaxf(acc[8+t][r]+b1f[8+t],0.f);
    }
    char* hb = (char*)hbuf + row*512;
    *(b8*)(hb + ((((2*lr)  ^(row&7))&31)<<4)) = p0;
    *(b8*)(hb + ((((2*lr+1)^(row&7))&31)<<4)) = p1;
  }
#pragma unroll
  for (int t=0;t<16;++t) acc[t]=(f4){0.f,0.f,0.f,0.f};
  for (int kb=0;kb<8;++kb){
    stageW(w2t, kb, wstage, tid);
    __syncthreads();
    int row = w*16 + lr;
    b8 af = *(const b8*)((char*)hbuf + row*512 + ((((kb*4+lq)^(row&7))&31)<<4));
#pragma unroll
    for (int t=0;t<16;++t){
      b8 bb = readB(wstage, 16*lr+t, lq);
      acc[t] = __builtin_amdgcn_mfma_f32_16x16x32_bf16(af, bb, acc[t], 0,0,0);
    }
    __syncthreads();
  }
#pragma unroll
  for (int r=0;r<4;++r){
    int row = row0 + w*16 + 4*lq + r;
    const f4* rp = (const f4*)(qbuf + (size_t)row*256 + 16*lr);
    float vv[16];
#pragma unroll
    for (int u=0;u<4;++u){
      f4 rr = rp[u];
#pragma unroll
      for (int e2=0;e2<4;++e2) vv[4*u+e2] = acc[4*u+e2][r] + b2f[4*u+e2] + rr[e2];
    }
    float s1 = 0.f;
#pragma unroll
    for (int t=0;t<16;++t) s1 += vv[t];
#pragma unroll
    for (int st=1;st<16;st<<=1) s1 += __shfl_xor(s1,st,64);
    float mu = s1 * (1.f/256.f);
    float s2 = 0.f;
#pragma unroll
    for (int t=0;t<16;++t){ float d = vv[t]-mu; s2 += d*d; }
#pragma unroll
    for (int st=1;st<16;st<<=1) s2 += __shfl_xor(s2,st,64);
    float rinv = 1.f/sqrtf(s2*(1.f/256.f) + 1e-6f);
    float* op = dout + (size_t)row*256 + 16*lr;
#pragma unroll
    for (int u=0;u<4;++u){
      f4 ov = { (vv[4*u+0]-mu)*rinv*gf[4*u+0] + bf2[4*u+0],
                (vv[4*u+1]-mu)*rinv*gf[4*u+1] + bf2[4*u+1],
                (vv[4*u+2]-mu)*rinv*gf[4*u+2] + bf2[4*u+2],
                (vv[4*u+3]-mu)*rinv*gf[4*u+3] + bf2[4*u+3] };
      ((f4*)op)[u] = ov;
    }
  }
}

// ----------------------------------------------------------------
extern "C" void kernel_launch(void* const* d_in, const int* in_sizes, int n_in,
                              void* d_out, int out_size, void* d_ws, size_t ws_size,
                              hipStream_t stream) {
  const float* x    = (const float*)d_in[0];
  const float* pos  = (const float*)d_in[1];
  const float* nrm  = (const float*)d_in[2];
  const float *qW1=(const float*)d_in[4],  *qb1=(const float*)d_in[5],
              *qW2=(const float*)d_in[6],  *qb2=(const float*)d_in[7];
  const float *kW1=(const float*)d_in[8],  *kb1=(const float*)d_in[9],
              *kW2=(const float*)d_in[10], *kb2=(const float*)d_in[11];
  const float *vW1=(const float*)d_in[12], *vb1=(const float*)d_in[13],
              *vW2=(const float*)d_in[14], *vb2=(const float*)d_in[15];
  const float *pW1=(const float*)d_in[16], *pb1=(const float*)d_in[17],
              *pW2=(const float*)d_in[18], *pb2=(const float*)d_in[19];
  const float *oW1=(const float*)d_in[20], *ob1=(const float*)d_in[21],
              *oW2=(const float*)d_in[22], *ob2=(const float*)d_in[23];
  const float *lng=(const float*)d_in[24], *lnb=(const float*)d_in[25];

  __bf16* wt   = (__bf16*)d_ws;                        // 9*65536 bf16
  __bf16* xb   = wt + (size_t)9*65536;                 // BN*256 bf16
  float*  pos4 = (float*)(xb + (size_t)BN*256);        // BN*4 f32
  int*    knn  = (int*)(pos4 + (size_t)BN*4);          // BN*16 i32
  float*  qbuf = (float*)(knn + (size_t)BN*16);        // BN*256 f32
  __bf16* kfb  = (__bf16*)(qbuf + (size_t)BN*256);     // BN*256 bf16
  __bf16* vfb  = kfb + (size_t)BN*256;
  __bf16* o1   = vfb + (size_t)BN*256;

  k_wt9 <<<dim3(64,11), 256, 0, stream>>>(qW1,qW2,kW1,kW2,vW1,vW2,pW2,oW1,oW2, wt, pos, pos4, x, xb);
  k_knn <<<dim3(NP/32, NBATCH), 256, 0, stream>>>(pos, knn);
  k_mlp <<<dim3(BN/128, 3), 256, 0, stream>>>(xb, wt, qb1,qb2,kb1,kb2,vb1,vb2, qbuf, kfb, vfb);
  k_attn<<<BN/8, 256, 0, stream>>>(nrm, pos4, knn, qbuf, kfb, vfb, wt, pW1, pb1, pb2, o1);
  k_out <<<BN/64, 256, 0, stream>>>(o1, wt, ob1, ob2, qbuf, lng, lnb, (float*)d_out);
}

// Round 7
// 567.560 us; speedup vs baseline: 1.2208x; 1.2208x over previous
//
#include <hip/hip_runtime.h>
#include <math.h>

#define NBATCH 4
#define NP 4096
#define BN (NBATCH*NP)
#define KCAP 256

typedef unsigned short u16; typedef unsigned int u32; typedef unsigned long long u64;
typedef __attribute__((ext_vector_type(4))) float f4;
typedef __attribute__((ext_vector_type(8))) __bf16 b8;

__device__ __forceinline__ void load16(const float* __restrict__ p, float* d){
  const f4* q = (const f4*)p;
  f4 a0=q[0], a1=q[1], a2=q[2], a3=q[3];
#pragma unroll
  for (int e=0;e<4;++e){ d[e]=a0[e]; d[4+e]=a1[e]; d[8+e]=a2[e]; d[12+e]=a3[e]; }
}

// 16 KB [256 c][32 k] staging tile swizzle (k_mlp / k_attn / k_out)
__device__ __forceinline__ int waddr(int c, int u){
  return ((c*64) ^ ((c&16)<<2)) + (((u ^ (c>>5)) & 3)<<4);
}
__device__ __forceinline__ void stageW(const __bf16* __restrict__ wsrc, int kb, __bf16* lds, int tid){
#pragma unroll
  for (int p=0;p<4;++p){
    int flat = p*256 + tid;
    int c = flat>>2, u = flat&3;
    b8 v = *(const b8*)(wsrc + (size_t)c*256 + kb*32 + u*8);
    *(b8*)((char*)lds + waddr(c,u)) = v;
  }
}
__device__ __forceinline__ b8 readB(const __bf16* lds, int c, int lq){
  return *(const b8*)((const char*)lds + waddr(c,lq));
}

// ---------------------------------------------------------------- y<9: transpose 9 f32 mats -> bf16 [out][in]
// y==9: pos -> pos4 ; y==10: x f32 -> bf16
__global__ __launch_bounds__(256) void k_wt9(
    const float* a0,const float* a1,const float* a2,const float* a3,const float* a4,
    const float* a5,const float* a6,const float* a7,const float* a8, __bf16* wt,
    const float* __restrict__ pos, float* __restrict__ pos4,
    const float* __restrict__ x, __bf16* __restrict__ xb)
{
  __shared__ float T[32][33];
  int m = blockIdx.y;
  if (m == 9){
    int n = blockIdx.x*256 + threadIdx.x;
    f4 v = {pos[n*3+0], pos[n*3+1], pos[n*3+2], 0.0f};
    ((f4*)pos4)[n] = v;
    return;
  }
  if (m == 10){
    int base = (blockIdx.x*256 + threadIdx.x);
    for (int it=0; it<32; ++it){
      int i = (base + it*16384)*8;
      f4 a = ((const f4*)(x+i))[0];
      f4 b = ((const f4*)(x+i))[1];
      b8 o;
#pragma unroll
      for (int e=0;e<4;++e){ o[e]=(__bf16)a[e]; o[4+e]=(__bf16)b[e]; }
      *(b8*)(xb+i) = o;
    }
    return;
  }
  const float* s;
  switch(m){ case 0:s=a0;break; case 1:s=a1;break; case 2:s=a2;break; case 3:s=a3;break;
             case 4:s=a4;break; case 5:s=a5;break; case 6:s=a6;break; case 7:s=a7;break; default:s=a8;break; }
  int tile = blockIdx.x;
  int ti = (tile>>3)*32, to = (tile&7)*32;
  int tx = threadIdx.x & 31, ty = threadIdx.x >> 5;
#pragma unroll
  for (int rr=0;rr<4;++rr){
    int i = ti + ty + rr*8;
    T[tx][ty+rr*8] = s[(size_t)i*256 + to + tx];
  }
  __syncthreads();
#pragma unroll
  for (int rr=0;rr<4;++rr){
    int o = to + ty + rr*8;
    wt[(size_t)m*65536 + (size_t)o*256 + ti + tx] = (__bf16)T[ty+rr*8][tx];
  }
}

// ---------------------------------------------------------------- exact KNN (top-16 by (d2,idx))
// Spill-free: candidate-major min sweep (no d2 array), per-row recompute selection sweep.
__global__ __launch_bounds__(256) void k_knn(const float* __restrict__ pos, int* __restrict__ knnout){
#pragma clang fp contract(off)
  __shared__ f4  lp[NP];          // x,y,z,sq  (64 KB)
  __shared__ u64 buf[4][KCAP];
  int tid = threadIdx.x, lane = tid & 63, w = tid >> 6;
  int b = blockIdx.y;
  int rowbase = blockIdx.x * 32;

  for (int i = tid; i < NP; i += 256){
    float x = pos[(size_t)(b*NP+i)*3+0];
    float y = pos[(size_t)(b*NP+i)*3+1];
    float z = pos[(size_t)(b*NP+i)*3+2];
    f4 v = {x, y, z, (x*x + y*y) + z*z};
    lp[i] = v;
  }
  __syncthreads();

  // this wave's 8 row coords in registers (broadcast LDS reads)
  float xn[8], yn[8], zn[8], sqn[8];
#pragma unroll
  for (int r=0;r<8;++r){
    f4 p = lp[rowbase + w*8 + r];
    xn[r]=p[0]; yn[r]=p[1]; zn[r]=p[2]; sqn[r]=p[3];
  }

  // sweep 1: candidate-major, per-row lane minima only (no d2 storage)
  float mn[8];
#pragma unroll
  for (int r=0;r<8;++r) mn[r] = 3.4e38f;
#pragma unroll 4
  for (int t = 0; t < 64; ++t){
    f4 pm = lp[t*64 + lane];
#pragma unroll
    for (int r=0;r<8;++r){
      float dot = (xn[r]*pm[0] + yn[r]*pm[1]) + zn[r]*pm[2];
      float d2 = (sqn[r] + pm[3]) - 2.0f*dot;
      d2 = fmaxf(d2, 0.0f);
      mn[r] = fminf(mn[r], d2);
    }
  }

  u64* mybuf = buf[w];
#pragma unroll
  for (int r=0;r<8;++r){
    int n = rowbase + w*8 + r;
    // bitonic sort of lane minima (ascending across 64 lanes) -> 16th = T1
    float v = mn[r];
#pragma unroll
    for (int k = 2; k <= 64; k <<= 1){
#pragma unroll
      for (int j = k>>1; j >= 1; j >>= 1){
        float o = __shfl_xor(v, j, 64);
        float lo = fminf(v,o), hi = fmaxf(v,o);
        v = (((lane & k) == 0) == ((lane & j) == 0)) ? lo : hi;
      }
    }
    float T1 = __shfl(v, 15, 64);   // >=16 candidates have d2 <= T1

    // selection sweep: recompute d2 on the fly (identical expression -> bit-identical)
    int cnt = 0;
#pragma unroll 2
    for (int t = 0; t < 64; ++t){
      f4 pm = lp[t*64 + lane];
      float dot = (xn[r]*pm[0] + yn[r]*pm[1]) + zn[r]*pm[2];
      float d2 = (sqn[r] + pm[3]) - 2.0f*dot;
      d2 = fmaxf(d2, 0.0f);
      bool pass = (d2 <= T1);
      u64 mk = __ballot(pass);
      if (pass){
        int p = cnt + __popcll(mk & ((1ull<<lane)-1ull));
        if (p < KCAP) mybuf[p] = (((u64)__float_as_uint(d2))<<32) | (u32)(t*64+lane);
      }
      cnt += __popcll(mk);
    }
    int* orow = knnout + (size_t)(b*NP + n)*16;
    if (cnt <= KCAP){
      for (int base = 0; base < cnt; base += 64){
        int e = base + lane;
        u64 mykey = (e < cnt) ? mybuf[e] : ~0ull;
        int rank = 0;
        for (int m2 = 0; m2 < cnt; ++m2) rank += (mybuf[m2] < mykey) ? 1 : 0;
        if (e < cnt && rank < 16) orow[rank] = b*NP + (int)(u32)(mykey & 0xffffffffull);
      }
    } else {
      // exact fallback (rare): per-lane sorted top-16 insertion with recompute + wave merge
      float dd[16]; int ii[16];
#pragma unroll
      for (int i2=0;i2<16;++i2){ dd[i2]=3.4e38f; ii[i2]=0x7fffffff; }
      for (int t=0;t<64;++t){
        f4 pm = lp[t*64 + lane];
        float dot = (xn[r]*pm[0] + yn[r]*pm[1]) + zn[r]*pm[2];
        float d2 = (sqn[r] + pm[3]) - 2.0f*dot;
        d2 = fmaxf(d2, 0.0f);
        int j = t*64+lane;
        if (d2 < dd[15]){
#pragma unroll
          for (int i2=15;i2>0;--i2){
            bool up  = d2 < dd[i2-1];
            bool in2 = d2 < dd[i2];
            float nv = up ? dd[i2-1] : (in2 ? d2 : dd[i2]);
            int   ni = up ? ii[i2-1] : (in2 ? j  : ii[i2]);
            dd[i2]=nv; ii[i2]=ni;
          }
          if (d2 < dd[0]){ dd[0]=d2; ii[0]=j; }
        }
      }
      for (int rr=0;rr<16;++rr){
        u64 key = (((u64)__float_as_uint(dd[0]))<<32) | (u32)ii[0];
        u64 m3 = key;
#pragma unroll
        for (int s=1;s<64;s<<=1){ u64 o3 = __shfl_xor(m3, s, 64); m3 = (o3<m3)?o3:m3; }
        if (key == m3){
#pragma unroll
          for (int i2=0;i2<15;++i2){ dd[i2]=dd[i2+1]; ii[i2]=ii[i2+1]; }
          dd[15]=3.4e38f; ii[15]=0x7fffffff;
        }
        if (lane == rr) orow[rr] = b*NP + (int)(u32)(m3 & 0xffffffffull);
      }
    }
  }
}

// ---------------------------------------------------------------- fused 2-layer MLP (q/k/v), M=128, LDS-staged B
__global__ __launch_bounds__(256,2) void k_mlp(
  const __bf16* __restrict__ xb, const __bf16* __restrict__ wt,
  const float* qb1,const float* qb2,const float* kb1,const float* kb2,
  const float* vb1,const float* vb2,
  float* __restrict__ qout, __bf16* __restrict__ kfout, __bf16* __restrict__ vfout)
{
  int which = blockIdx.y;
  const __bf16* w1t = wt + (size_t)which*2*65536;
  const __bf16* w2t = w1t + 65536;
  const float* b1 = (which==0)?qb1:((which==1)?kb1:vb1);
  const float* b2 = (which==0)?qb2:((which==1)?kb2:vb2);
  __shared__ __align__(16) __bf16 wstage[8192];
  __shared__ __align__(16) __bf16 hbuf[128*256];
  int tid=threadIdx.x, lane=tid&63, w=tid>>6, lr=lane&15, lq=lane>>4;
  int row0 = blockIdx.x*128;

  float b1f[16], b2f[16];
  load16(b1+16*lr, b1f); load16(b2+16*lr, b2f);

  f4 acc[2][16];
#pragma unroll
  for (int tt=0;tt<2;++tt)
#pragma unroll
    for (int t=0;t<16;++t) acc[tt][t]=(f4){0.f,0.f,0.f,0.f};

  for (int kb=0;kb<8;++kb){
    stageW(w1t, kb, wstage, tid);
    __syncthreads();
    b8 af[2];
#pragma unroll
    for (int tt=0;tt<2;++tt)
      af[tt] = *(const b8*)(xb + (size_t)(row0 + (w+tt*4)*16 + lr)*256 + kb*32 + lq*8);
#pragma unroll
    for (int t=0;t<16;++t){
      b8 bb = readB(wstage, 16*lr+t, lq);
      acc[0][t] = __builtin_amdgcn_mfma_f32_16x16x32_bf16(af[0], bb, acc[0][t], 0,0,0);
      acc[1][t] = __builtin_amdgcn_mfma_f32_16x16x32_bf16(af[1], bb, acc[1][t], 0,0,0);
    }
    __syncthreads();
  }
#pragma unroll
  for (int tt=0;tt<2;++tt){
#pragma unroll
    for (int r=0;r<4;++r){
      int row = (w+tt*4)*16 + 4*lq + r;
      b8 p0,p1;
#pragma unroll
      for (int t=0;t<8;++t){
        p0[t]=(__bf16)fmaxf(acc[tt][t][r]  +b1f[t],  0.f);
        p1[t]=(__bf16)fmaxf(acc[tt][8+t][r]+b1f[8+t],0.f);
      }
      char* hb = (char*)hbuf + row*512;
      *(b8*)(hb + ((((2*lr)  ^(row&7))&31)<<4)) = p0;
      *(b8*)(hb + ((((2*lr+1)^(row&7))&31)<<4)) = p1;
    }
  }
#pragma unroll
  for (int tt=0;tt<2;++tt)
#pragma unroll
    for (int t=0;t<16;++t) acc[tt][t]=(f4){0.f,0.f,0.f,0.f};
  for (int kb=0;kb<8;++kb){
    stageW(w2t, kb, wstage, tid);
    __syncthreads();
    b8 af[2];
#pragma unroll
    for (int tt=0;tt<2;++tt){
      int row = (w+tt*4)*16 + lr;
      af[tt] = *(const b8*)((char*)hbuf + row*512 + ((((kb*4+lq)^(row&7))&31)<<4));
    }
#pragma unroll
    for (int t=0;t<16;++t){
      b8 bb = readB(wstage, 16*lr+t, lq);
      acc[0][t] = __builtin_amdgcn_mfma_f32_16x16x32_bf16(af[0], bb, acc[0][t], 0,0,0);
      acc[1][t] = __builtin_amdgcn_mfma_f32_16x16x32_bf16(af[1], bb, acc[1][t], 0,0,0);
    }
    __syncthreads();
  }
  if (which == 0){
#pragma unroll
    for (int tt=0;tt<2;++tt){
#pragma unroll
      for (int r=0;r<4;++r){
        float* qp = qout + (size_t)(row0 + (w+tt*4)*16 + 4*lq + r)*256 + 16*lr;
#pragma unroll
        for (int u2=0;u2<4;++u2){
          f4 vv;
#pragma unroll
          for (int e2=0;e2<4;++e2)
            vv[e2] = (tt ? acc[1][4*u2+e2][r] : acc[0][4*u2+e2][r]) + b2f[4*u2+e2];
          ((f4*)qp)[u2] = vv;
        }
      }
    }
  } else {
    __bf16* outp = (which==1) ? kfout : vfout;
#pragma unroll
    for (int tt=0;tt<2;++tt){
#pragma unroll
      for (int r=0;r<4;++r){
        b8 p0,p1;
#pragma unroll
        for (int t=0;t<8;++t){
          float a0v = tt ? acc[1][t][r]   : acc[0][t][r];
          float a1v = tt ? acc[1][8+t][r] : acc[0][8+t][r];
          p0[t]=(__bf16)(a0v+b2f[t]);
          p1[t]=(__bf16)(a1v+b2f[8+t]);
        }
        __bf16* op = outp + (size_t)(row0 + (w+tt*4)*16 + 4*lq + r)*256 + 16*lr;
        *(b8*)op = p0; *((b8*)op+1) = p1;
      }
    }
  }
}

// ---------------------------------------------------------------- fused pe-MLP + gather + attention, 8 pts/block
__global__ __launch_bounds__(256,2) void k_attn(
  const float* __restrict__ normal, const float* __restrict__ pos4,
  const int* __restrict__ knn, const float* __restrict__ qbuf,
  const __bf16* __restrict__ kf, const __bf16* __restrict__ vf,
  const __bf16* __restrict__ wt,
  const float* __restrict__ pw1, const float* __restrict__ pb1, const float* __restrict__ pb2,
  __bf16* __restrict__ o1)
{
  __shared__ __align__(16) __bf16 wstage[8192];
  const __bf16* pw2t = wt + (size_t)6*65536;
  int tid=threadIdx.x, lane=tid&63, w=tid>>6, lr=lane&15, lq=lane>>4;
  int pt0 = blockIdx.x*8 + w;
  int idx[2]; float rv[2], tv[2];
#pragma unroll
  for (int pp=0;pp<2;++pp){
    int p = pt0 + pp*4;
    int j = knn[(size_t)p*16 + lr];
    idx[pp] = j;
    f4 pn = ((const f4*)pos4)[p];
    f4 pj = ((const f4*)pos4)[j];
    float rx=pn[0]-pj[0], ry=pn[1]-pj[1], rz=pn[2]-pj[2];
    float nx=normal[(size_t)p*3], ny=normal[(size_t)p*3+1], nz=normal[(size_t)p*3+2];
    float nn = fmaxf(sqrtf(nx*nx+ny*ny+nz*nz), 1e-12f);
    nx/=nn; ny/=nn; nz/=nn;
    float sqr = rx*rx+ry*ry+rz*rz;
    float r = (sqr>0.f)?sqrtf(sqr):0.f;
    float dt = rx*nx+ry*ny+rz*nz;
    float ratio = fminf(fmaxf(dt/(r+1e-8f),-1.f),1.f);
    rv[pp]=r; tv[pp]=acosf(ratio);
  }

  f4 acc[2][16];
#pragma unroll
  for (int pp=0;pp<2;++pp)
#pragma unroll
    for (int t=0;t<16;++t) acc[pp][t]=(f4){0.f,0.f,0.f,0.f};

  for (int kb=0;kb<8;++kb){
    stageW(pw2t, kb, wstage, tid);
    __syncthreads();
    int kk = kb*32 + lq*8;
    f4 w0a = *(const f4*)(pw1 + kk);
    f4 w0b = *(const f4*)(pw1 + kk + 4);
    f4 w1a = *(const f4*)(pw1 + 256 + kk);
    f4 w1b = *(const f4*)(pw1 + 256 + kk + 4);
    f4 bba = *(const f4*)(pb1 + kk);
    f4 bbb = *(const f4*)(pb1 + kk + 4);
    b8 af[2];
#pragma unroll
    for (int pp=0;pp<2;++pp){
      float r=rv[pp], th=tv[pp];
#pragma unroll
      for (int j2=0;j2<4;++j2){
        af[pp][j2]   = (__bf16)fmaxf(r*w0a[j2] + th*w1a[j2] + bba[j2], 0.f);
        af[pp][4+j2] = (__bf16)fmaxf(r*w0b[j2] + th*w1b[j2] + bbb[j2], 0.f);
      }
    }
#pragma unroll
    for (int t=0;t<16;++t){
      b8 bb = readB(wstage, 16*lr+t, lq);
      acc[0][t] = __builtin_amdgcn_mfma_f32_16x16x32_bf16(af[0], bb, acc[0][t], 0,0,0);
      acc[1][t] = __builtin_amdgcn_mfma_f32_16x16x32_bf16(af[1], bb, acc[1][t], 0,0,0);
    }
    __syncthreads();
  }

  float pb2f[16];
  load16(pb2 + 16*lr, pb2f);
#pragma unroll
  for (int pp=0;pp<2;++pp){
    int ptv = pt0 + pp*4;
    float qv[16];
    load16(qbuf + (size_t)ptv*256 + 16*lr, qv);
    int idxv = idx[pp];
    float sc[4];
#pragma unroll
    for (int r=0;r<4;++r){
      int j = __shfl(idxv, 4*lq + r, 64);
      const b8* kr = (const b8*)(kf + (size_t)j*256 + 16*lr);
      b8 k0 = kr[0], k1 = kr[1];
      float s = 0.f;
#pragma unroll
      for (int t=0;t<8;++t){
        float a0v = pp ? acc[1][t][r]   : acc[0][t][r];
        float a1v = pp ? acc[1][8+t][r] : acc[0][8+t][r];
        s += ((float)k0[t] + a0v + pb2f[t]  ) * qv[t];
        s += ((float)k1[t] + a1v + pb2f[8+t]) * qv[8+t];
      }
      sc[r]=s;
    }
#pragma unroll
    for (int st=1; st<16; st<<=1){
#pragma unroll
      for (int r=0;r<4;++r) sc[r] += __shfl_xor(sc[r], st, 64);
    }
#pragma unroll
    for (int r=0;r<4;++r) sc[r] *= 0.0625f;
    float mx = fmaxf(fmaxf(sc[0],sc[1]), fmaxf(sc[2],sc[3]));
    mx = fmaxf(mx, __shfl_xor(mx,16,64));
    mx = fmaxf(mx, __shfl_xor(mx,32,64));
    float e[4]; float ssum=0.f;
#pragma unroll
    for (int r=0;r<4;++r){ e[r]=expf(sc[r]-mx); ssum+=e[r]; }
    ssum += __shfl_xor(ssum,16,64);
    ssum += __shfl_xor(ssum,32,64);
    float inv = 1.f/ssum;
    float o[16];
#pragma unroll
    for (int t=0;t<16;++t) o[t]=0.f;
#pragma unroll
    for (int r=0;r<4;++r){
      int j = __shfl(idxv, 4*lq + r, 64);
      const b8* vr = (const b8*)(vf + (size_t)j*256 + 16*lr);
      b8 v0 = vr[0], v1 = vr[1];
      float aw = e[r]*inv;
#pragma unroll
      for (int t=0;t<8;++t){
        float a0v = pp ? acc[1][t][r]   : acc[0][t][r];
        float a1v = pp ? acc[1][8+t][r] : acc[0][8+t][r];
        o[t]   += aw*((float)v0[t] + a0v + pb2f[t]);
        o[8+t] += aw*((float)v1[t] + a1v + pb2f[8+t]);
      }
    }
#pragma unroll
    for (int t=0;t<16;++t){
      o[t] += __shfl_xor(o[t],16,64);
      o[t] += __shfl_xor(o[t],32,64);
    }
    if (lq==0){
      b8 p0,p1;
#pragma unroll
      for (int t=0;t<8;++t){ p0[t]=(__bf16)o[t]; p1[t]=(__bf16)o[8+t]; }
      __bf16* op = o1 + (size_t)ptv*256 + 16*lr;
      *(b8*)op = p0; *((b8*)op+1) = p1;
    }
  }
}

// ---------------------------------------------------------------- fc_out + residual + LayerNorm, M=64, f32 out
__global__ __launch_bounds__(256,2) void k_out(
  const __bf16* __restrict__ o1, const __bf16* __restrict__ wt,
  const float* __restrict__ ob1, const float* __restrict__ ob2,
  const float* __restrict__ qbuf,
  const float* __restrict__ lng, const float* __restrict__ lnb,
  float* __restrict__ dout)
{
  const __bf16* w1t = wt + (size_t)7*65536;
  const __bf16* w2t = wt + (size_t)8*65536;
  __shared__ __align__(16) __bf16 wstage[8192];
  __shared__ __align__(16) __bf16 hbuf[64*256];
  int tid=threadIdx.x, lane=tid&63, w=tid>>6, lr=lane&15, lq=lane>>4;
  int row0 = blockIdx.x*64;

  float b1f[16], b2f[16], gf[16], bf2[16];
  load16(ob1+16*lr, b1f); load16(ob2+16*lr, b2f);
  load16(lng+16*lr, gf);  load16(lnb+16*lr, bf2);

  f4 acc[16];
#pragma unroll
  for (int t=0;t<16;++t) acc[t]=(f4){0.f,0.f,0.f,0.f};
  for (int kb=0;kb<8;++kb){
    stageW(w1t, kb, wstage, tid);
    __syncthreads();
    b8 af = *(const b8*)(o1 + (size_t)(row0 + w*16 + lr)*256 + kb*32 + lq*8);
#pragma unroll
    for (int t=0;t<16;++t){
      b8 bb = readB(wstage, 16*lr+t, lq);
      acc[t] = __builtin_amdgcn_mfma_f32_16x16x32_bf16(af, bb, acc[t], 0,0,0);
    }
    __syncthreads();
  }
#pragma unroll
  for (int r=0;r<4;++r){
    int row = w*16 + 4*lq + r;
    b8 p0,p1;
#pragma unroll
    for (int t=0;t<8;++t){
      p0[t]=(__bf16)fmaxf(acc[t][r]  +b1f[t],  0.f);
      p1[t]=(__bf16)fmaxf(acc[8+t][r]+b1f[8+t],0.f);
    }
    char* hb = (char*)hbuf + row*512;
    *(b8*)(hb + ((((2*lr)  ^(row&7))&31)<<4)) = p0;
    *(b8*)(hb + ((((2*lr+1)^(row&7))&31)<<4)) = p1;
  }
#pragma unroll
  for (int t=0;t<16;++t) acc[t]=(f4){0.f,0.f,0.f,0.f};
  for (int kb=0;kb<8;++kb){
    stageW(w2t, kb, wstage, tid);
    __syncthreads();
    int row = w*16 + lr;
    b8 af = *(const b8*)((char*)hbuf + row*512 + ((((kb*4+lq)^(row&7))&31)<<4));
#pragma unroll
    for (int t=0;t<16;++t){
      b8 bb = readB(wstage, 16*lr+t, lq);
      acc[t] = __builtin_amdgcn_mfma_f32_16x16x32_bf16(af, bb, acc[t], 0,0,0);
    }
    __syncthreads();
  }
#pragma unroll
  for (int r=0;r<4;++r){
    int row = row0 + w*16 + 4*lq + r;
    const f4* rp = (const f4*)(qbuf + (size_t)row*256 + 16*lr);
    float vv[16];
#pragma unroll
    for (int u=0;u<4;++u){
      f4 rr = rp[u];
#pragma unroll
      for (int e2=0;e2<4;++e2) vv[4*u+e2] = acc[4*u+e2][r] + b2f[4*u+e2] + rr[e2];
    }
    float s1 = 0.f;
#pragma unroll
    for (int t=0;t<16;++t) s1 += vv[t];
#pragma unroll
    for (int st=1;st<16;st<<=1) s1 += __shfl_xor(s1,st,64);
    float mu = s1 * (1.f/256.f);
    float s2 = 0.f;
#pragma unroll
    for (int t=0;t<16;++t){ float d = vv[t]-mu; s2 += d*d; }
#pragma unroll
    for (int st=1;st<16;st<<=1) s2 += __shfl_xor(s2,st,64);
    float rinv = 1.f/sqrtf(s2*(1.f/256.f) + 1e-6f);
    float* op = dout + (size_t)row*256 + 16*lr;
#pragma unroll
    for (int u=0;u<4;++u){
      f4 ov = { (vv[4*u+0]-mu)*rinv*gf[4*u+0] + bf2[4*u+0],
                (vv[4*u+1]-mu)*rinv*gf[4*u+1] + bf2[4*u+1],
                (vv[4*u+2]-mu)*rinv*gf[4*u+2] + bf2[4*u+2],
                (vv[4*u+3]-mu)*rinv*gf[4*u+3] + bf2[4*u+3] };
      ((f4*)op)[u] = ov;
    }
  }
}

// ----------------------------------------------------------------
extern "C" void kernel_launch(void* const* d_in, const int* in_sizes, int n_in,
                              void* d_out, int out_size, void* d_ws, size_t ws_size,
                              hipStream_t stream) {
  const float* x    = (const float*)d_in[0];
  const float* pos  = (const float*)d_in[1];
  const float* nrm  = (const float*)d_in[2];
  const float *qW1=(const float*)d_in[4],  *qb1=(const float*)d_in[5],
              *qW2=(const float*)d_in[6],  *qb2=(const float*)d_in[7];
  const float *kW1=(const float*)d_in[8],  *kb1=(const float*)d_in[9],
              *kW2=(const float*)d_in[10], *kb2=(const float*)d_in[11];
  const float *vW1=(const float*)d_in[12], *vb1=(const float*)d_in[13],
              *vW2=(const float*)d_in[14], *vb2=(const float*)d_in[15];
  const float *pW1=(const float*)d_in[16], *pb1=(const float*)d_in[17],
              *pW2=(const float*)d_in[18], *pb2=(const float*)d_in[19];
  const float *oW1=(const float*)d_in[20], *ob1=(const float*)d_in[21],
              *oW2=(const float*)d_in[22], *ob2=(const float*)d_in[23];
  const float *lng=(const float*)d_in[24], *lnb=(const float*)d_in[25];

  __bf16* wt   = (__bf16*)d_ws;                        // 9*65536 bf16
  __bf16* xb   = wt + (size_t)9*65536;                 // BN*256 bf16
  float*  pos4 = (float*)(xb + (size_t)BN*256);        // BN*4 f32
  int*    knn  = (int*)(pos4 + (size_t)BN*4);          // BN*16 i32
  float*  qbuf = (float*)(knn + (size_t)BN*16);        // BN*256 f32
  __bf16* kfb  = (__bf16*)(qbuf + (size_t)BN*256);     // BN*256 bf16
  __bf16* vfb  = kfb + (size_t)BN*256;
  __bf16* o1   = vfb + (size_t)BN*256;

  k_wt9 <<<dim3(64,11), 256, 0, stream>>>(qW1,qW2,kW1,kW2,vW1,vW2,pW2,oW1,oW2, wt, pos, pos4, x, xb);
  k_knn <<<dim3(NP/32, NBATCH), 256, 0, stream>>>(pos, knn);
  k_mlp <<<dim3(BN/128, 3), 256, 0, stream>>>(xb, wt, qb1,qb2,kb1,kb2,vb1,vb2, qbuf, kfb, vfb);
  k_attn<<<BN/8, 256, 0, stream>>>(nrm, pos4, knn, qbuf, kfb, vfb, wt, pW1, pb1, pb2, o1);
  k_out <<<BN/64, 256, 0, stream>>>(o1, wt, ob1, ob2, qbuf, lng, lnb, (float*)d_out);
}

// Round 8
// 558.951 us; speedup vs baseline: 1.2396x; 1.0154x over previous
//
#include <hip/hip_runtime.h>
#include <math.h>

#define NBATCH 4
#define NP 4096
#define BN (NBATCH*NP)
#define KCAP 256

typedef unsigned short u16; typedef unsigned int u32; typedef unsigned long long u64;
typedef __attribute__((ext_vector_type(4))) float f4;
typedef __attribute__((ext_vector_type(8))) __bf16 b8;

__device__ __forceinline__ void load16(const float* __restrict__ p, float* d){
  const f4* q = (const f4*)p;
  f4 a0=q[0], a1=q[1], a2=q[2], a3=q[3];
#pragma unroll
  for (int e=0;e<4;++e){ d[e]=a0[e]; d[4+e]=a1[e]; d[8+e]=a2[e]; d[12+e]=a3[e]; }
}

// 16 KB [256 c][32 k] staging tile swizzle (k_mlp / k_attn / k_out)
__device__ __forceinline__ int waddr(int c, int u){
  return ((c*64) ^ ((c&16)<<2)) + (((u ^ (c>>5)) & 3)<<4);
}
__device__ __forceinline__ void stageW(const __bf16* __restrict__ wsrc, int kb, __bf16* lds, int tid){
#pragma unroll
  for (int p=0;p<4;++p){
    int flat = p*256 + tid;
    int c = flat>>2, u = flat&3;
    b8 v = *(const b8*)(wsrc + (size_t)c*256 + kb*32 + u*8);
    *(b8*)((char*)lds + waddr(c,u)) = v;
  }
}
__device__ __forceinline__ b8 readB(const __bf16* lds, int c, int lq){
  return *(const b8*)((const char*)lds + waddr(c,lq));
}

// ---------------------------------------------------------------- merged prep + KNN
// blocks [0,512): exact KNN (top-16 by (d2,idx)), spill-free recompute scheme
// blocks [512,1216): id=blk-512, m=id>>6: m<9 -> transpose weight mat m (f32->bf16 [out][in]);
//                    m==9 -> pos->pos4; m==10 -> x f32->bf16
__global__ __launch_bounds__(256) void k_prep(
    const float* a0,const float* a1,const float* a2,const float* a3,const float* a4,
    const float* a5,const float* a6,const float* a7,const float* a8, __bf16* wt,
    const float* __restrict__ pos, float* __restrict__ pos4,
    const float* __restrict__ x, __bf16* __restrict__ xb,
    int* __restrict__ knnout)
{
#pragma clang fp contract(off)
  __shared__ __align__(16) char smem[73728];   // knn: lp 64KB + buf 8KB ; wt9: T overlay
  int tid = threadIdx.x;
  int blk = blockIdx.x;

  if (blk >= 512){
    int id = blk - 512;
    int m = id >> 6;
    int bx = id & 63;
    if (m == 9){
      int n = bx*256 + tid;
      f4 v = {pos[n*3+0], pos[n*3+1], pos[n*3+2], 0.0f};
      ((f4*)pos4)[n] = v;
      return;
    }
    if (m == 10){
      int base = bx*256 + tid;
      for (int it=0; it<32; ++it){
        int i = (base + it*16384)*8;
        f4 a = ((const f4*)(x+i))[0];
        f4 b = ((const f4*)(x+i))[1];
        b8 o;
#pragma unroll
        for (int e=0;e<4;++e){ o[e]=(__bf16)a[e]; o[4+e]=(__bf16)b[e]; }
        *(b8*)(xb+i) = o;
      }
      return;
    }
    const float* s;
    switch(m){ case 0:s=a0;break; case 1:s=a1;break; case 2:s=a2;break; case 3:s=a3;break;
               case 4:s=a4;break; case 5:s=a5;break; case 6:s=a6;break; case 7:s=a7;break; default:s=a8;break; }
    float (*T)[33] = (float(*)[33])smem;
    int ti = (bx>>3)*32, to = (bx&7)*32;
    int tx = tid & 31, ty = tid >> 5;
#pragma unroll
    for (int rr=0;rr<4;++rr){
      int i = ti + ty + rr*8;
      T[tx][ty+rr*8] = s[(size_t)i*256 + to + tx];
    }
    __syncthreads();
#pragma unroll
    for (int rr=0;rr<4;++rr){
      int o = to + ty + rr*8;
      wt[(size_t)m*65536 + (size_t)o*256 + ti + tx] = (__bf16)T[ty+rr*8][tx];
    }
    return;
  }

  // ---------------- KNN role ----------------
  f4*  lp  = (f4*)smem;                         // [NP] x,y,z,sq (64 KB)
  u64* bufw = (u64*)(smem + 65536);             // [4][KCAP] (8 KB)
  int lane = tid & 63, w = tid >> 6;
  int b = blk >> 7;
  int rowbase = (blk & 127) * 32;

  for (int i = tid; i < NP; i += 256){
    float px = pos[(size_t)(b*NP+i)*3+0];
    float py = pos[(size_t)(b*NP+i)*3+1];
    float pz = pos[(size_t)(b*NP+i)*3+2];
    f4 v = {px, py, pz, (px*px + py*py) + pz*pz};
    lp[i] = v;
  }
  __syncthreads();

  // this wave's 8 row coords in registers (broadcast LDS reads)
  float xn[8], yn[8], zn[8], sqn[8];
#pragma unroll
  for (int r=0;r<8;++r){
    f4 p = lp[rowbase + w*8 + r];
    xn[r]=p[0]; yn[r]=p[1]; zn[r]=p[2]; sqn[r]=p[3];
  }

  // sweep 1: candidate-major, per-row lane minima only (no d2 storage)
  float mn[8];
#pragma unroll
  for (int r=0;r<8;++r) mn[r] = 3.4e38f;
#pragma unroll 4
  for (int t = 0; t < 64; ++t){
    f4 pm = lp[t*64 + lane];
#pragma unroll
    for (int r=0;r<8;++r){
      float dot = (xn[r]*pm[0] + yn[r]*pm[1]) + zn[r]*pm[2];
      float d2 = (sqn[r] + pm[3]) - 2.0f*dot;
      d2 = fmaxf(d2, 0.0f);
      mn[r] = fminf(mn[r], d2);
    }
  }

  u64* mybuf = bufw + w*KCAP;
#pragma unroll
  for (int r=0;r<8;++r){
    int n = rowbase + w*8 + r;
    // bitonic sort of lane minima (ascending across 64 lanes) -> 16th = T1
    float v = mn[r];
#pragma unroll
    for (int k = 2; k <= 64; k <<= 1){
#pragma unroll
      for (int j = k>>1; j >= 1; j >>= 1){
        float o = __shfl_xor(v, j, 64);
        float lo = fminf(v,o), hi = fmaxf(v,o);
        v = (((lane & k) == 0) == ((lane & j) == 0)) ? lo : hi;
      }
    }
    float T1 = __shfl(v, 15, 64);   // >=16 candidates have d2 <= T1

    // selection sweep: recompute d2 on the fly (identical expression -> bit-identical)
    int cnt = 0;
#pragma unroll 2
    for (int t = 0; t < 64; ++t){
      f4 pm = lp[t*64 + lane];
      float dot = (xn[r]*pm[0] + yn[r]*pm[1]) + zn[r]*pm[2];
      float d2 = (sqn[r] + pm[3]) - 2.0f*dot;
      d2 = fmaxf(d2, 0.0f);
      bool pass = (d2 <= T1);
      u64 mk = __ballot(pass);
      if (pass){
        int p = cnt + __popcll(mk & ((1ull<<lane)-1ull));
        if (p < KCAP) mybuf[p] = (((u64)__float_as_uint(d2))<<32) | (u32)(t*64+lane);
      }
      cnt += __popcll(mk);
    }
    int* orow = knnout + (size_t)(b*NP + n)*16;
    if (cnt <= KCAP){
      for (int base = 0; base < cnt; base += 64){
        int e = base + lane;
        u64 mykey = (e < cnt) ? mybuf[e] : ~0ull;
        int rank = 0;
        for (int m2 = 0; m2 < cnt; ++m2) rank += (mybuf[m2] < mykey) ? 1 : 0;
        if (e < cnt && rank < 16) orow[rank] = b*NP + (int)(u32)(mykey & 0xffffffffull);
      }
    } else {
      // exact fallback (rare): per-lane sorted top-16 insertion with recompute + wave merge
      float dd[16]; int ii[16];
#pragma unroll
      for (int i2=0;i2<16;++i2){ dd[i2]=3.4e38f; ii[i2]=0x7fffffff; }
      for (int t=0;t<64;++t){
        f4 pm = lp[t*64 + lane];
        float dot = (xn[r]*pm[0] + yn[r]*pm[1]) + zn[r]*pm[2];
        float d2 = (sqn[r] + pm[3]) - 2.0f*dot;
        d2 = fmaxf(d2, 0.0f);
        int j = t*64+lane;
        if (d2 < dd[15]){
#pragma unroll
          for (int i2=15;i2>0;--i2){
            bool up  = d2 < dd[i2-1];
            bool in2 = d2 < dd[i2];
            float nv = up ? dd[i2-1] : (in2 ? d2 : dd[i2]);
            int   ni = up ? ii[i2-1] : (in2 ? j  : ii[i2]);
            dd[i2]=nv; ii[i2]=ni;
          }
          if (d2 < dd[0]){ dd[0]=d2; ii[0]=j; }
        }
      }
      for (int rr=0;rr<16;++rr){
        u64 key = (((u64)__float_as_uint(dd[0]))<<32) | (u32)ii[0];
        u64 m3 = key;
#pragma unroll
        for (int s=1;s<64;s<<=1){ u64 o3 = __shfl_xor(m3, s, 64); m3 = (o3<m3)?o3:m3; }
        if (key == m3){
#pragma unroll
          for (int i2=0;i2<15;++i2){ dd[i2]=dd[i2+1]; ii[i2]=ii[i2+1]; }
          dd[15]=3.4e38f; ii[15]=0x7fffffff;
        }
        if (lane == rr) orow[rr] = b*NP + (int)(u32)(m3 & 0xffffffffull);
      }
    }
  }
}

// ---------------------------------------------------------------- fused 2-layer MLP (q/k/v), M=128, LDS-staged B
__global__ __launch_bounds__(256,2) void k_mlp(
  const __bf16* __restrict__ xb, const __bf16* __restrict__ wt,
  const float* qb1,const float* qb2,const float* kb1,const float* kb2,
  const float* vb1,const float* vb2,
  float* __restrict__ qout, __bf16* __restrict__ kfout, __bf16* __restrict__ vfout)
{
  int which = blockIdx.y;
  const __bf16* w1t = wt + (size_t)which*2*65536;
  const __bf16* w2t = w1t + 65536;
  const float* b1 = (which==0)?qb1:((which==1)?kb1:vb1);
  const float* b2 = (which==0)?qb2:((which==1)?kb2:vb2);
  __shared__ __align__(16) __bf16 wstage[8192];
  __shared__ __align__(16) __bf16 hbuf[128*256];
  int tid=threadIdx.x, lane=tid&63, w=tid>>6, lr=lane&15, lq=lane>>4;
  int row0 = blockIdx.x*128;

  float b1f[16], b2f[16];
  load16(b1+16*lr, b1f); load16(b2+16*lr, b2f);

  f4 acc[2][16];
#pragma unroll
  for (int tt=0;tt<2;++tt)
#pragma unroll
    for (int t=0;t<16;++t) acc[tt][t]=(f4){0.f,0.f,0.f,0.f};

  for (int kb=0;kb<8;++kb){
    stageW(w1t, kb, wstage, tid);
    __syncthreads();
    b8 af[2];
#pragma unroll
    for (int tt=0;tt<2;++tt)
      af[tt] = *(const b8*)(xb + (size_t)(row0 + (w+tt*4)*16 + lr)*256 + kb*32 + lq*8);
#pragma unroll
    for (int t=0;t<16;++t){
      b8 bb = readB(wstage, 16*lr+t, lq);
      acc[0][t] = __builtin_amdgcn_mfma_f32_16x16x32_bf16(af[0], bb, acc[0][t], 0,0,0);
      acc[1][t] = __builtin_amdgcn_mfma_f32_16x16x32_bf16(af[1], bb, acc[1][t], 0,0,0);
    }
    __syncthreads();
  }
#pragma unroll
  for (int tt=0;tt<2;++tt){
#pragma unroll
    for (int r=0;r<4;++r){
      int row = (w+tt*4)*16 + 4*lq + r;
      b8 p0,p1;
#pragma unroll
      for (int t=0;t<8;++t){
        p0[t]=(__bf16)fmaxf(acc[tt][t][r]  +b1f[t],  0.f);
        p1[t]=(__bf16)fmaxf(acc[tt][8+t][r]+b1f[8+t],0.f);
      }
      char* hb = (char*)hbuf + row*512;
      *(b8*)(hb + ((((2*lr)  ^(row&7))&31)<<4)) = p0;
      *(b8*)(hb + ((((2*lr+1)^(row&7))&31)<<4)) = p1;
    }
  }
#pragma unroll
  for (int tt=0;tt<2;++tt)
#pragma unroll
    for (int t=0;t<16;++t) acc[tt][t]=(f4){0.f,0.f,0.f,0.f};
  for (int kb=0;kb<8;++kb){
    stageW(w2t, kb, wstage, tid);
    __syncthreads();
    b8 af[2];
#pragma unroll
    for (int tt=0;tt<2;++tt){
      int row = (w+tt*4)*16 + lr;
      af[tt] = *(const b8*)((char*)hbuf + row*512 + ((((kb*4+lq)^(row&7))&31)<<4));
    }
#pragma unroll
    for (int t=0;t<16;++t){
      b8 bb = readB(wstage, 16*lr+t, lq);
      acc[0][t] = __builtin_amdgcn_mfma_f32_16x16x32_bf16(af[0], bb, acc[0][t], 0,0,0);
      acc[1][t] = __builtin_amdgcn_mfma_f32_16x16x32_bf16(af[1], bb, acc[1][t], 0,0,0);
    }
    __syncthreads();
  }
  if (which == 0){
#pragma unroll
    for (int tt=0;tt<2;++tt){
#pragma unroll
      for (int r=0;r<4;++r){
        float* qp = qout + (size_t)(row0 + (w+tt*4)*16 + 4*lq + r)*256 + 16*lr;
#pragma unroll
        for (int u2=0;u2<4;++u2){
          f4 vv;
#pragma unroll
          for (int e2=0;e2<4;++e2)
            vv[e2] = (tt ? acc[1][4*u2+e2][r] : acc[0][4*u2+e2][r]) + b2f[4*u2+e2];
          ((f4*)qp)[u2] = vv;
        }
      }
    }
  } else {
    __bf16* outp = (which==1) ? kfout : vfout;
#pragma unroll
    for (int tt=0;tt<2;++tt){
#pragma unroll
      for (int r=0;r<4;++r){
        b8 p0,p1;
#pragma unroll
        for (int t=0;t<8;++t){
          float a0v = tt ? acc[1][t][r]   : acc[0][t][r];
          float a1v = tt ? acc[1][8+t][r] : acc[0][8+t][r];
          p0[t]=(__bf16)(a0v+b2f[t]);
          p1[t]=(__bf16)(a1v+b2f[8+t]);
        }
        __bf16* op = outp + (size_t)(row0 + (w+tt*4)*16 + 4*lq + r)*256 + 16*lr;
        *(b8*)op = p0; *((b8*)op+1) = p1;
      }
    }
  }
}

// ---------------------------------------------------------------- fused pe-MLP + gather + attention, 8 pts/block
__global__ __launch_bounds__(256,2) void k_attn(
  const float* __restrict__ normal, const float* __restrict__ pos4,
  const int* __restrict__ knn, const float* __restrict__ qbuf,
  const __bf16* __restrict__ kf, const __bf16* __restrict__ vf,
  const __bf16* __restrict__ wt,
  const float* __restrict__ pw1, const float* __restrict__ pb1, const float* __restrict__ pb2,
  __bf16* __restrict__ o1)
{
  __shared__ __align__(16) __bf16 wstage[8192];
  const __bf16* pw2t = wt + (size_t)6*65536;
  int tid=threadIdx.x, lane=tid&63, w=tid>>6, lr=lane&15, lq=lane>>4;
  int pt0 = blockIdx.x*8 + w;
  int idx[2]; float rv[2], tv[2];
#pragma unroll
  for (int pp=0;pp<2;++pp){
    int p = pt0 + pp*4;
    int j = knn[(size_t)p*16 + lr];
    idx[pp] = j;
    f4 pn = ((const f4*)pos4)[p];
    f4 pj = ((const f4*)pos4)[j];
    float rx=pn[0]-pj[0], ry=pn[1]-pj[1], rz=pn[2]-pj[2];
    float nx=normal[(size_t)p*3], ny=normal[(size_t)p*3+1], nz=normal[(size_t)p*3+2];
    float nn = fmaxf(sqrtf(nx*nx+ny*ny+nz*nz), 1e-12f);
    nx/=nn; ny/=nn; nz/=nn;
    float sqr = rx*rx+ry*ry+rz*rz;
    float r = (sqr>0.f)?sqrtf(sqr):0.f;
    float dt = rx*nx+ry*ny+rz*nz;
    float ratio = fminf(fmaxf(dt/(r+1e-8f),-1.f),1.f);
    rv[pp]=r; tv[pp]=acosf(ratio);
  }

  f4 acc[2][16];
#pragma unroll
  for (int pp=0;pp<2;++pp)
#pragma unroll
    for (int t=0;t<16;++t) acc[pp][t]=(f4){0.f,0.f,0.f,0.f};

  for (int kb=0;kb<8;++kb){
    stageW(pw2t, kb, wstage, tid);
    __syncthreads();
    int kk = kb*32 + lq*8;
    f4 w0a = *(const f4*)(pw1 + kk);
    f4 w0b = *(const f4*)(pw1 + kk + 4);
    f4 w1a = *(const f4*)(pw1 + 256 + kk);
    f4 w1b = *(const f4*)(pw1 + 256 + kk + 4);
    f4 bba = *(const f4*)(pb1 + kk);
    f4 bbb = *(const f4*)(pb1 + kk + 4);
    b8 af[2];
#pragma unroll
    for (int pp=0;pp<2;++pp){
      float r=rv[pp], th=tv[pp];
#pragma unroll
      for (int j2=0;j2<4;++j2){
        af[pp][j2]   = (__bf16)fmaxf(r*w0a[j2] + th*w1a[j2] + bba[j2], 0.f);
        af[pp][4+j2] = (__bf16)fmaxf(r*w0b[j2] + th*w1b[j2] + bbb[j2], 0.f);
      }
    }
#pragma unroll
    for (int t=0;t<16;++t){
      b8 bb = readB(wstage, 16*lr+t, lq);
      acc[0][t] = __builtin_amdgcn_mfma_f32_16x16x32_bf16(af[0], bb, acc[0][t], 0,0,0);
      acc[1][t] = __builtin_amdgcn_mfma_f32_16x16x32_bf16(af[1], bb, acc[1][t], 0,0,0);
    }
    __syncthreads();
  }

  float pb2f[16];
  load16(pb2 + 16*lr, pb2f);
#pragma unroll
  for (int pp=0;pp<2;++pp){
    int ptv = pt0 + pp*4;
    float qv[16];
    load16(qbuf + (size_t)ptv*256 + 16*lr, qv);
    int idxv = idx[pp];
    float sc[4];
#pragma unroll
    for (int r=0;r<4;++r){
      int j = __shfl(idxv, 4*lq + r, 64);
      const b8* kr = (const b8*)(kf + (size_t)j*256 + 16*lr);
      b8 k0 = kr[0], k1 = kr[1];
      float s = 0.f;
#pragma unroll
      for (int t=0;t<8;++t){
        float a0v = pp ? acc[1][t][r]   : acc[0][t][r];
        float a1v = pp ? acc[1][8+t][r] : acc[0][8+t][r];
        s += ((float)k0[t] + a0v + pb2f[t]  ) * qv[t];
        s += ((float)k1[t] + a1v + pb2f[8+t]) * qv[8+t];
      }
      sc[r]=s;
    }
#pragma unroll
    for (int st=1; st<16; st<<=1){
#pragma unroll
      for (int r=0;r<4;++r) sc[r] += __shfl_xor(sc[r], st, 64);
    }
#pragma unroll
    for (int r=0;r<4;++r) sc[r] *= 0.0625f;
    float mx = fmaxf(fmaxf(sc[0],sc[1]), fmaxf(sc[2],sc[3]));
    mx = fmaxf(mx, __shfl_xor(mx,16,64));
    mx = fmaxf(mx, __shfl_xor(mx,32,64));
    float e[4]; float ssum=0.f;
#pragma unroll
    for (int r=0;r<4;++r){ e[r]=expf(sc[r]-mx); ssum+=e[r]; }
    ssum += __shfl_xor(ssum,16,64);
    ssum += __shfl_xor(ssum,32,64);
    float inv = 1.f/ssum;
    float o[16];
#pragma unroll
    for (int t=0;t<16;++t) o[t]=0.f;
#pragma unroll
    for (int r=0;r<4;++r){
      int j = __shfl(idxv, 4*lq + r, 64);
      const b8* vr = (const b8*)(vf + (size_t)j*256 + 16*lr);
      b8 v0 = vr[0], v1 = vr[1];
      float aw = e[r]*inv;
#pragma unroll
      for (int t=0;t<8;++t){
        float a0v = pp ? acc[1][t][r]   : acc[0][t][r];
        float a1v = pp ? acc[1][8+t][r] : acc[0][8+t][r];
        o[t]   += aw*((float)v0[t] + a0v + pb2f[t]);
        o[8+t] += aw*((float)v1[t] + a1v + pb2f[8+t]);
      }
    }
#pragma unroll
    for (int t=0;t<16;++t){
      o[t] += __shfl_xor(o[t],16,64);
      o[t] += __shfl_xor(o[t],32,64);
    }
    if (lq==0){
      b8 p0,p1;
#pragma unroll
      for (int t=0;t<8;++t){ p0[t]=(__bf16)o[t]; p1[t]=(__bf16)o[8+t]; }
      __bf16* op = o1 + (size_t)ptv*256 + 16*lr;
      *(b8*)op = p0; *((b8*)op+1) = p1;
    }
  }
}

// ---------------------------------------------------------------- fc_out + residual + LayerNorm, M=64, f32 out
__global__ __launch_bounds__(256,2) void k_out(
  const __bf16* __restrict__ o1, const __bf16* __restrict__ wt,
  const float* __restrict__ ob1, const float* __restrict__ ob2,
  const float* __restrict__ qbuf,
  const float* __restrict__ lng, const float* __restrict__ lnb,
  float* __restrict__ dout)
{
  const __bf16* w1t = wt + (size_t)7*65536;
  const __bf16* w2t = wt + (size_t)8*65536;
  __shared__ __align__(16) __bf16 wstage[8192];
  __shared__ __align__(16) __bf16 hbuf[64*256];
  int tid=threadIdx.x, lane=tid&63, w=tid>>6, lr=lane&15, lq=lane>>4;
  int row0 = blockIdx.x*64;

  float b1f[16], b2f[16], gf[16], bf2[16];
  load16(ob1+16*lr, b1f); load16(ob2+16*lr, b2f);
  load16(lng+16*lr, gf);  load16(lnb+16*lr, bf2);

  f4 acc[16];
#pragma unroll
  for (int t=0;t<16;++t) acc[t]=(f4){0.f,0.f,0.f,0.f};
  for (int kb=0;kb<8;++kb){
    stageW(w1t, kb, wstage, tid);
    __syncthreads();
    b8 af = *(const b8*)(o1 + (size_t)(row0 + w*16 + lr)*256 + kb*32 + lq*8);
#pragma unroll
    for (int t=0;t<16;++t){
      b8 bb = readB(wstage, 16*lr+t, lq);
      acc[t] = __builtin_amdgcn_mfma_f32_16x16x32_bf16(af, bb, acc[t], 0,0,0);
    }
    __syncthreads();
  }
#pragma unroll
  for (int r=0;r<4;++r){
    int row = w*16 + 4*lq + r;
    b8 p0,p1;
#pragma unroll
    for (int t=0;t<8;++t){
      p0[t]=(__bf16)fmaxf(acc[t][r]  +b1f[t],  0.f);
      p1[t]=(__bf16)fmaxf(acc[8+t][r]+b1f[8+t],0.f);
    }
    char* hb = (char*)hbuf + row*512;
    *(b8*)(hb + ((((2*lr)  ^(row&7))&31)<<4)) = p0;
    *(b8*)(hb + ((((2*lr+1)^(row&7))&31)<<4)) = p1;
  }
#pragma unroll
  for (int t=0;t<16;++t) acc[t]=(f4){0.f,0.f,0.f,0.f};
  for (int kb=0;kb<8;++kb){
    stageW(w2t, kb, wstage, tid);
    __syncthreads();
    int row = w*16 + lr;
    b8 af = *(const b8*)((char*)hbuf + row*512 + ((((kb*4+lq)^(row&7))&31)<<4));
#pragma unroll
    for (int t=0;t<16;++t){
      b8 bb = readB(wstage, 16*lr+t, lq);
      acc[t] = __builtin_amdgcn_mfma_f32_16x16x32_bf16(af, bb, acc[t], 0,0,0);
    }
    __syncthreads();
  }
#pragma unroll
  for (int r=0;r<4;++r){
    int row = row0 + w*16 + 4*lq + r;
    const f4* rp = (const f4*)(qbuf + (size_t)row*256 + 16*lr);
    float vv[16];
#pragma unroll
    for (int u=0;u<4;++u){
      f4 rr = rp[u];
#pragma unroll
      for (int e2=0;e2<4;++e2) vv[4*u+e2] = acc[4*u+e2][r] + b2f[4*u+e2] + rr[e2];
    }
    float s1 = 0.f;
#pragma unroll
    for (int t=0;t<16;++t) s1 += vv[t];
#pragma unroll
    for (int st=1;st<16;st<<=1) s1 += __shfl_xor(s1,st,64);
    float mu = s1 * (1.f/256.f);
    float s2 = 0.f;
#pragma unroll
    for (int t=0;t<16;++t){ float d = vv[t]-mu; s2 += d*d; }
#pragma unroll
    for (int st=1;st<16;st<<=1) s2 += __shfl_xor(s2,st,64);
    float rinv = 1.f/sqrtf(s2*(1.f/256.f) + 1e-6f);
    float* op = dout + (size_t)row*256 + 16*lr;
#pragma unroll
    for (int u=0;u<4;++u){
      f4 ov = { (vv[4*u+0]-mu)*rinv*gf[4*u+0] + bf2[4*u+0],
                (vv[4*u+1]-mu)*rinv*gf[4*u+1] + bf2[4*u+1],
                (vv[4*u+2]-mu)*rinv*gf[4*u+2] + bf2[4*u+2],
                (vv[4*u+3]-mu)*rinv*gf[4*u+3] + bf2[4*u+3] };
      ((f4*)op)[u] = ov;
    }
  }
}

// ----------------------------------------------------------------
extern "C" void kernel_launch(void* const* d_in, const int* in_sizes, int n_in,
                              void* d_out, int out_size, void* d_ws, size_t ws_size,
                              hipStream_t stream) {
  const float* x    = (const float*)d_in[0];
  const float* pos  = (const float*)d_in[1];
  const float* nrm  = (const float*)d_in[2];
  const float *qW1=(const float*)d_in[4],  *qb1=(const float*)d_in[5],
              *qW2=(const float*)d_in[6],  *qb2=(const float*)d_in[7];
  const float *kW1=(const float*)d_in[8],  *kb1=(const float*)d_in[9],
              *kW2=(const float*)d_in[10], *kb2=(const float*)d_in[11];
  const float *vW1=(const float*)d_in[12], *vb1=(const float*)d_in[13],
              *vW2=(const float*)d_in[14], *vb2=(const float*)d_in[15];
  const float *pW1=(const float*)d_in[16], *pb1=(const float*)d_in[17],
              *pW2=(const float*)d_in[18], *pb2=(const float*)d_in[19];
  const float *oW1=(const float*)d_in[20], *ob1=(const float*)d_in[21],
              *oW2=(const float*)d_in[22], *ob2=(const float*)d_in[23];
  const float *lng=(const float*)d_in[24], *lnb=(const float*)d_in[25];

  __bf16* wt   = (__bf16*)d_ws;                        // 9*65536 bf16
  __bf16* xb   = wt + (size_t)9*65536;                 // BN*256 bf16
  float*  pos4 = (float*)(xb + (size_t)BN*256);        // BN*4 f32
  int*    knn  = (int*)(pos4 + (size_t)BN*4);          // BN*16 i32
  float*  qbuf = (float*)(knn + (size_t)BN*16);        // BN*256 f32
  __bf16* kfb  = (__bf16*)(qbuf + (size_t)BN*256);     // BN*256 bf16
  __bf16* vfb  = kfb + (size_t)BN*256;
  __bf16* o1   = vfb + (size_t)BN*256;

  k_prep<<<1216, 256, 0, stream>>>(qW1,qW2,kW1,kW2,vW1,vW2,pW2,oW1,oW2, wt,
                                   pos, pos4, x, xb, knn);
  k_mlp <<<dim3(BN/128, 3), 256, 0, stream>>>(xb, wt, qb1,qb2,kb1,kb2,vb1,vb2, qbuf, kfb, vfb);
  k_attn<<<BN/8, 256, 0, stream>>>(nrm, pos4, knn, qbuf, kfb, vfb, wt, pW1, pb1, pb2, o1);
  k_out <<<BN/64, 256, 0, stream>>>(o1, wt, ob1, ob2, qbuf, lng, lnb, (float*)d_out);
}